// Round 3
// baseline (8114.208 us; speedup 1.0000x reference)
//
#include <hip/hip_runtime.h>
#include <math.h>

#define T_TOT  16384     // B*S
#define S_LEN  1024
#define B_SZ   16
#define DM     512
#define DIN    576
#define DFF    2048
#define NHEAD  8
#define DHEAD  64
#define NK     50

#define OFF_SK 0
#define OFF_MS 819200
#define OFF_KP 851968
#define OFF_MP 1671168

typedef _Float16 half8 __attribute__((ext_vector_type(8)));
typedef _Float16 half4v __attribute__((ext_vector_type(4)));
typedef float floatx4 __attribute__((ext_vector_type(4)));

// ---------------------------------------------------------------- concat
__global__ __launch_bounds__(256) void concat_kernel(
    const float* __restrict__ st, const float* __restrict__ ac,
    const float* __restrict__ go, float* __restrict__ out)
{
    int idx = blockIdx.x * 256 + threadIdx.x;            // float4 id
    int row = idx / 144;                                 // DIN/4 = 144
    int c4  = idx - row * 144;
    float4 v;
    if (c4 < 64)      v = ((const float4*)st)[(size_t)row * 64 + c4];
    else if (c4 < 80) v = ((const float4*)ac)[(size_t)row * 16 + (c4 - 64)];
    else              v = ((const float4*)go)[(size_t)row * 64 + (c4 - 80)];
    ((float4*)out)[idx] = v;
}

// ---------------------------------------------------------------- conv act f32 -> f16 hi/lo planes (fragment-ordered)
// planes: chunk for subtile (sm, sk) at ((sk*(M>>4)+sm)*64 + lane)*8 halves,
// lane = (row&15) + ((k>>3)&3)*16, j = k&7.  Tile: 256 rows x 32 k.
__global__ __launch_bounds__(256) void conv_act(
    const float* __restrict__ A, int lda,
    _Float16* __restrict__ Ph, _Float16* __restrict__ Pl, int M)
{
    __shared__ _Float16 lh[16 * 512];
    __shared__ _Float16 ll[16 * 512];
    const int tid = threadIdx.x;
    const int sk = blockIdx.x;
    const int m0 = blockIdx.y * 256;
    const int SM = M >> 4;
#pragma unroll
    for (int i = 0; i < 8; ++i) {
        int idx = tid + i * 256;               // 2048 float4
        int rl = idx >> 3, kq = idx & 7;
        float4 f = *(const float4*)&A[(size_t)(m0 + rl) * lda + sk * 32 + kq * 4];
        int lane = (rl & 15) + (kq >> 1) * 16;
        int off = ((rl >> 4) * 64 + lane) * 8 + (kq & 1) * 4;
        _Float16 h0 = (_Float16)f.x, h1 = (_Float16)f.y, h2 = (_Float16)f.z, h3 = (_Float16)f.w;
        half4v hv = {h0, h1, h2, h3};
        half4v lv = {(_Float16)((f.x - (float)h0) * 2048.f),
                     (_Float16)((f.y - (float)h1) * 2048.f),
                     (_Float16)((f.z - (float)h2) * 2048.f),
                     (_Float16)((f.w - (float)h3) * 2048.f)};
        *(half4v*)&lh[off] = hv;
        *(half4v*)&ll[off] = lv;
    }
    __syncthreads();
#pragma unroll
    for (int i = 0; i < 8; ++i) {
        int idx = tid + i * 256;               // 2048 16B-chunks
        int plane = idx >> 10, q = idx & 1023;
        int s = q >> 6, ln = q & 63;
        uint4 v = *(const uint4*)&(plane ? ll : lh)[(s * 64 + ln) * 8];
        _Float16* P = plane ? Pl : Ph;
        *(uint4*)&P[((size_t)(sk * SM + (m0 >> 4) + s) * 64 + ln) * 8] = v;
    }
}

// ---------------------------------------------------------------- conv weight f32 [K,N] -> B-fragment planes
// chunk (sn, sk) at ((sk*(N>>4)+sn)*64 + lane)*8, lane=(n&15)+((k>>3)&3)*16, j=k&7.
// Tile: 32 k x 128 n.
__global__ __launch_bounds__(256) void conv_w(
    const float* __restrict__ W, int N,
    _Float16* __restrict__ Ph, _Float16* __restrict__ Pl)
{
    __shared__ _Float16 lh[8 * 512];
    __shared__ _Float16 ll[8 * 512];
    const int tid = threadIdx.x;
    const int sk = blockIdx.y;
    const int n0 = blockIdx.x * 128;
    const int SN = N >> 4;
#pragma unroll
    for (int i = 0; i < 4; ++i) {
        int idx = tid + i * 256;               // 1024 float4
        int k = idx >> 5, n4 = idx & 31;
        float4 f = *(const float4*)&W[(size_t)(sk * 32 + k) * N + n0 + n4 * 4];
        int kb = (k >> 3) & 3, j = k & 7;
        float vv[4] = {f.x, f.y, f.z, f.w};
#pragma unroll
        for (int t = 0; t < 4; ++t) {
            int nl = n4 * 4 + t;
            int off = ((nl >> 4) * 64 + (nl & 15) + kb * 16) * 8 + j;
            _Float16 h = (_Float16)vv[t];
            lh[off] = h;
            ll[off] = (_Float16)((vv[t] - (float)h) * 2048.f);
        }
    }
    __syncthreads();
#pragma unroll
    for (int i = 0; i < 4; ++i) {
        int idx = tid + i * 256;               // 1024 chunks
        int plane = idx >> 9, q = idx & 511;
        int s = q >> 6, ln = q & 63;
        uint4 v = *(const uint4*)&(plane ? ll : lh)[(s * 64 + ln) * 8];
        _Float16* P = plane ? Pl : Ph;
        *(uint4*)&P[((size_t)(sk * SN + (n0 >> 4) + s) * 64 + ln) * 8] = v;
    }
}

// ---------------------------------------------------------------- split-f16 MFMA GEMM
// C[M,N] = A@W + bias from pre-converted fragment-ordered planes.
// 128x128 tile, BK=32, 4 waves (2x2 of 64x64), 16x16x32 MFMA, dual accumulator.
__global__ __launch_bounds__(256, 2) void gemm_mfma(
    const _Float16* __restrict__ Ah, const _Float16* __restrict__ Al,
    const _Float16* __restrict__ Bh, const _Float16* __restrict__ Bl,
    const float* __restrict__ bias, float* __restrict__ C, int ldc,
    int M, int N, int K, int relu, int mb0, int mrow_sub)
{
    __shared__ _Float16 ldsf[16384];   // 32KB: [Ah|Al|Bh|Bl] x 8 subtiles x 512
    const int tid = threadIdx.x;
    const int lane = tid & 63, wave = tid >> 6;
    const int wm = wave >> 1, wn = wave & 1;
    const int m0 = (blockIdx.y + mb0) * 128;
    const int n0 = blockIdx.x * 128;
    const int SM = M >> 4, SN = N >> 4;
    const int sm0 = m0 >> 4, sn0 = n0 >> 4;

    const uint4* srcs[8];
    int strid[8];
#pragma unroll
    for (int i = 0; i < 8; ++i) {
        int s = (i & 1) * 4 + wave;
        if (i < 4) {
            const _Float16* P = (i < 2) ? Ah : Al;
            srcs[i] = (const uint4*)P + ((size_t)(sm0 + s) * 64 + lane);
            strid[i] = SM * 64;
        } else {
            const _Float16* P = (i < 6) ? Bh : Bl;
            srcs[i] = (const uint4*)P + ((size_t)(sn0 + s) * 64 + lane);
            strid[i] = SN * 64;
        }
    }

    floatx4 accM[4][4], accC[4][4];
#pragma unroll
    for (int i = 0; i < 4; ++i)
#pragma unroll
        for (int j = 0; j < 4; ++j) {
            accM[i][j] = floatx4{0.f, 0.f, 0.f, 0.f};
            accC[i][j] = floatx4{0.f, 0.f, 0.f, 0.f};
        }

    uint4 st[8];
#pragma unroll
    for (int i = 0; i < 8; ++i) st[i] = srcs[i][0];

    const int nkt = K >> 5;
    const int abase = (wm * 4 * 64 + lane) * 8;
    const int bbase = 8192 + (wn * 4 * 64 + lane) * 8;
    for (int kt = 0; kt < nkt; ++kt) {
        __syncthreads();
#pragma unroll
        for (int i = 0; i < 8; ++i)
            *(uint4*)&ldsf[(tid + i * 256) * 8] = st[i];
        __syncthreads();
        if (kt + 1 < nkt) {
#pragma unroll
            for (int i = 0; i < 8; ++i)
                st[i] = srcs[i][(size_t)(kt + 1) * strid[i]];
        }
        half8 a_h[4], a_l[4];
#pragma unroll
        for (int mi = 0; mi < 4; ++mi) {
            a_h[mi] = *(const half8*)&ldsf[abase + mi * 512];
            a_l[mi] = *(const half8*)&ldsf[abase + 4096 + mi * 512];
        }
#pragma unroll
        for (int ni = 0; ni < 4; ++ni) {
            half8 b_h = *(const half8*)&ldsf[bbase + ni * 512];
            half8 b_l = *(const half8*)&ldsf[bbase + 4096 + ni * 512];
#pragma unroll
            for (int mi = 0; mi < 4; ++mi) {
                accM[mi][ni] = __builtin_amdgcn_mfma_f32_16x16x32_f16(a_h[mi], b_h, accM[mi][ni], 0, 0, 0);
                accC[mi][ni] = __builtin_amdgcn_mfma_f32_16x16x32_f16(a_l[mi], b_h, accC[mi][ni], 0, 0, 0);
                accC[mi][ni] = __builtin_amdgcn_mfma_f32_16x16x32_f16(a_h[mi], b_l, accC[mi][ni], 0, 0, 0);
            }
        }
    }

    const int colq = lane & 15, rq = lane >> 4;
#pragma unroll
    for (int ni = 0; ni < 4; ++ni) {
        int col = n0 + wn * 64 + ni * 16 + colq;
        float bv = bias[col];
#pragma unroll
        for (int mi = 0; mi < 4; ++mi) {
            floatx4 d = accM[mi][ni] + accC[mi][ni] * (1.0f / 2048.0f);
            int row0 = m0 - mrow_sub + wm * 64 + mi * 16 + rq * 4;
#pragma unroll
            for (int r = 0; r < 4; ++r) {
                float v = d[r] + bv;
                if (relu) v = fmaxf(v, 0.f);
                C[(size_t)(row0 + r) * ldc + col] = v;
            }
        }
    }
}

// ---------------------------------------------------------------- GEMM f32 (small heads: N=50, N=2)
__global__ __launch_bounds__(256) void gemm_f32(
    const float* __restrict__ A, int lda,
    const float* __restrict__ W, const float* __restrict__ bias,
    float* __restrict__ C, int ldc, int M, int K, int N, int relu)
{
    __shared__ float As[16][128];
    __shared__ float Bs[16][128];
    const int tid = threadIdx.x;
    const int tx = tid & 15, ty = tid >> 4;
    const int m0 = blockIdx.y * 128;
    const int n0 = blockIdx.x * 128;
    const bool nfull = (n0 + 128 <= N) && ((N & 3) == 0);

    float acc[8][8];
#pragma unroll
    for (int i = 0; i < 8; ++i)
#pragma unroll
        for (int j = 0; j < 8; ++j) acc[i][j] = 0.f;

    const int nkt = K >> 4;
    for (int kt = 0; kt < nkt; ++kt) {
#pragma unroll
        for (int i = 0; i < 2; ++i) {
            int q = tid * 2 + i;
            int r = q >> 2, c = (q & 3) * 4;
            float4 v = *(const float4*)(A + (size_t)(m0 + r) * lda + kt * 16 + c);
            As[c + 0][r] = v.x; As[c + 1][r] = v.y;
            As[c + 2][r] = v.z; As[c + 3][r] = v.w;
        }
#pragma unroll
        for (int i = 0; i < 2; ++i) {
            int q = tid * 2 + i;
            int kr = q >> 5, c = (q & 31) * 4;
            const float* wr = W + (size_t)(kt * 16 + kr) * N;
            int col = n0 + c;
            float4 v;
            if (nfull) v = *(const float4*)(wr + col);
            else {
                v.x = (col     < N) ? wr[col]     : 0.f;
                v.y = (col + 1 < N) ? wr[col + 1] : 0.f;
                v.z = (col + 2 < N) ? wr[col + 2] : 0.f;
                v.w = (col + 3 < N) ? wr[col + 3] : 0.f;
            }
            *(float4*)&Bs[kr][c] = v;
        }
        __syncthreads();
#pragma unroll
        for (int kk = 0; kk < 16; ++kk) {
            float a[8], bb[8];
            *(float4*)&a[0]  = *(const float4*)&As[kk][ty * 8];
            *(float4*)&a[4]  = *(const float4*)&As[kk][ty * 8 + 4];
            *(float4*)&bb[0] = *(const float4*)&Bs[kk][tx * 8];
            *(float4*)&bb[4] = *(const float4*)&Bs[kk][tx * 8 + 4];
#pragma unroll
            for (int i = 0; i < 8; ++i)
#pragma unroll
                for (int j = 0; j < 8; ++j)
                    acc[i][j] = fmaf(a[i], bb[j], acc[i][j]);
        }
        __syncthreads();
    }

    float bv[8];
#pragma unroll
    for (int j = 0; j < 8; ++j) {
        int col = n0 + tx * 8 + j;
        bv[j] = (col < N) ? bias[col] : 0.f;
    }
#pragma unroll
    for (int i = 0; i < 8; ++i) {
        int row = m0 + ty * 8 + i;
#pragma unroll
        for (int j = 0; j < 8; ++j) {
            int col = n0 + tx * 8 + j;
            if (col < N) {
                float v = acc[i][j] + bv[j];
                if (relu) v = fmaxf(v, 0.f);
                C[(size_t)row * ldc + col] = v;
            }
        }
    }
}

// ---------------------------------------------------------------- attention (flash, f32, causal)
__global__ __launch_bounds__(256) void attn_f32(
    const float* __restrict__ qkv, float* __restrict__ out)
{
    __shared__ float Qs[64 * 68];
    __shared__ float KP[64 * 68];
    __shared__ float Vs[64 * 64];

    const int tid = threadIdx.x;
    const int qi = blockIdx.x, h = blockIdx.y, b = blockIdx.z;
    const int row = tid >> 2, cg = tid & 3;
    const size_t base = (size_t)b * S_LEN * 2048 + (size_t)h * DHEAD;

#pragma unroll
    for (int i = 0; i < 4; ++i) {
        int q = tid + i * 256;
        int r = q >> 4, d0 = (q & 15) * 4;
        float4 v = *(const float4*)&qkv[base + (size_t)(qi * 64 + r) * 2048 + d0];
        *(float4*)&Qs[r * 68 + d0] = v;
    }

    float o[16];
#pragma unroll
    for (int j = 0; j < 16; ++j) o[j] = 0.f;
    float mrun = -INFINITY, lrun = 0.f;

    for (int kt = 0; kt <= qi; ++kt) {
        __syncthreads();
#pragma unroll
        for (int i = 0; i < 4; ++i) {
            int q = tid + i * 256;
            int r = q >> 4, d0 = (q & 15) * 4;
            float4 kv = *(const float4*)&qkv[base + 512 + (size_t)(kt * 64 + r) * 2048 + d0];
            KP[(d0 + 0) * 68 + r] = kv.x; KP[(d0 + 1) * 68 + r] = kv.y;
            KP[(d0 + 2) * 68 + r] = kv.z; KP[(d0 + 3) * 68 + r] = kv.w;
            float4 vv = *(const float4*)&qkv[base + 1024 + (size_t)(kt * 64 + r) * 2048 + d0];
            *(float4*)&Vs[r * 64 + d0] = vv;
        }
        __syncthreads();

        float s[16];
#pragma unroll
        for (int j = 0; j < 16; ++j) s[j] = 0.f;
#pragma unroll 8
        for (int d = 0; d < 64; ++d) {
            float qv = Qs[row * 68 + d];
#pragma unroll
            for (int j4 = 0; j4 < 4; ++j4) {
                float4 kv = *(const float4*)&KP[d * 68 + cg * 16 + j4 * 4];
                s[j4 * 4 + 0] = fmaf(qv, kv.x, s[j4 * 4 + 0]);
                s[j4 * 4 + 1] = fmaf(qv, kv.y, s[j4 * 4 + 1]);
                s[j4 * 4 + 2] = fmaf(qv, kv.z, s[j4 * 4 + 2]);
                s[j4 * 4 + 3] = fmaf(qv, kv.w, s[j4 * 4 + 3]);
            }
        }
        const bool diag = (kt == qi);
#pragma unroll
        for (int j = 0; j < 16; ++j) {
            float sv = s[j] * 0.125f;
            if (diag && (cg * 16 + j) > row) sv = -1e9f;
            s[j] = sv;
        }
        float tm = s[0];
#pragma unroll
        for (int j = 1; j < 16; ++j) tm = fmaxf(tm, s[j]);
        tm = fmaxf(tm, __shfl_xor(tm, 1));
        tm = fmaxf(tm, __shfl_xor(tm, 2));
        float mn = fmaxf(mrun, tm);
        float scale = expf(mrun - mn);
        float ls = 0.f;
#pragma unroll
        for (int j = 0; j < 16; ++j) { s[j] = expf(s[j] - mn); ls += s[j]; }
        ls += __shfl_xor(ls, 1);
        ls += __shfl_xor(ls, 2);
        lrun = lrun * scale + ls;
#pragma unroll
        for (int j = 0; j < 16; ++j) o[j] *= scale;
        mrun = mn;

        __syncthreads();
#pragma unroll
        for (int j4 = 0; j4 < 4; ++j4)
            *(float4*)&KP[row * 68 + cg * 16 + j4 * 4] =
                make_float4(s[j4 * 4], s[j4 * 4 + 1], s[j4 * 4 + 2], s[j4 * 4 + 3]);
        __syncthreads();

#pragma unroll 8
        for (int c = 0; c < 64; ++c) {
            float pv = KP[row * 68 + c];
#pragma unroll
            for (int j4 = 0; j4 < 4; ++j4) {
                float4 vv = *(const float4*)&Vs[c * 64 + cg * 16 + j4 * 4];
                o[j4 * 4 + 0] = fmaf(pv, vv.x, o[j4 * 4 + 0]);
                o[j4 * 4 + 1] = fmaf(pv, vv.y, o[j4 * 4 + 1]);
                o[j4 * 4 + 2] = fmaf(pv, vv.z, o[j4 * 4 + 2]);
                o[j4 * 4 + 3] = fmaf(pv, vv.w, o[j4 * 4 + 3]);
            }
        }
    }

    float invl = 1.0f / lrun;
    size_t ob = (size_t)(b * S_LEN + qi * 64 + row) * 2048 + (size_t)h * DHEAD + cg * 16;
#pragma unroll
    for (int j4 = 0; j4 < 4; ++j4)
        *(float4*)&out[ob + j4 * 4] =
            make_float4(o[j4 * 4] * invl, o[j4 * 4 + 1] * invl,
                        o[j4 * 4 + 2] * invl, o[j4 * 4 + 3] * invl);
}

// ---------------------------------------------------------------- residual + LayerNorm (in-place-safe on res/yout)
__global__ __launch_bounds__(256) void add_ln(
    const float* __restrict__ xin, const float* __restrict__ res,
    const float* __restrict__ gg, const float* __restrict__ bb,
    float* __restrict__ yout)
{
    int row = blockIdx.x, tid = threadIdx.x;
    __shared__ float red[8];
    size_t base = (size_t)row * DM + tid * 2;
    float2 u = *(const float2*)&xin[base];
    float2 v = *(const float2*)&res[base];
    float a = u.x + v.x, c = u.y + v.y;
    float s = a + c;
#pragma unroll
    for (int off = 32; off; off >>= 1) s += __shfl_xor(s, off);
    int wid = tid >> 6, lane = tid & 63;
    if (lane == 0) red[wid] = s;
    __syncthreads();
    float mu = (red[0] + red[1] + red[2] + red[3]) * (1.0f / 512.0f);
    float da = a - mu, dc = c - mu;
    float vs = da * da + dc * dc;
#pragma unroll
    for (int off = 32; off; off >>= 1) vs += __shfl_xor(vs, off);
    if (lane == 0) red[4 + wid] = vs;
    __syncthreads();
    float var = (red[4] + red[5] + red[6] + red[7]) * (1.0f / 512.0f);
    float rs = 1.0f / sqrtf(var + 1e-5f);
    float2 oo;
    oo.x = da * rs * gg[tid * 2]     + bb[tid * 2];
    oo.y = dc * rs * gg[tid * 2 + 1] + bb[tid * 2 + 1];
    *(float2*)&yout[base] = oo;
}

// ---------------------------------------------------------------- gumbel argmax (k, 50-way)
__global__ __launch_bounds__(256) void gumbel_k_kernel(
    const float* __restrict__ klog, const float* __restrict__ uk,
    int* __restrict__ kidx)
{
    int lane = threadIdx.x & 63;
    int p = blockIdx.x * 4 + (threadIdx.x >> 6);
    float z = -INFINITY;
    if (lane < NK) {
        float u = uk[(size_t)p * NK + lane];
        float g = -logf(-logf(u + 1e-10f) + 1e-10f);
        z = klog[(size_t)p * NK + lane] + g;
    }
    int idx = lane;
#pragma unroll
    for (int off = 1; off < 64; off <<= 1) {
        float oz = __shfl_xor(z, off);
        int   oi = __shfl_xor(idx, off);
        if (oz > z || (oz == z && oi < idx)) { z = oz; idx = oi; }
    }
    if (lane == 0) kidx[p] = idx;
}

// ---------------------------------------------------------------- gumbel argmax (m, 2-way)
__global__ __launch_bounds__(256) void gumbel_m_kernel(
    const float* __restrict__ mlog, const float* __restrict__ um,
    int* __restrict__ midx)
{
    int p = blockIdx.x * 256 + threadIdx.x;
    if (p >= T_TOT) return;
    float u0 = um[(size_t)p * 2], u1 = um[(size_t)p * 2 + 1];
    float g0 = -logf(-logf(u0 + 1e-10f) + 1e-10f);
    float g1 = -logf(-logf(u1 + 1e-10f) + 1e-10f);
    float z0 = mlog[(size_t)p * 2] + g0, z1 = mlog[(size_t)p * 2 + 1] + g1;
    midx[p] = (z1 > z0) ? 1 : 0;
}

// ---------------------------------------------------------------- per-batch cummax scan
__global__ void scan_kernel(const int* __restrict__ midx, int* __restrict__ rsel)
{
    __shared__ int sb[1024];
    int b = blockIdx.x, t = threadIdx.x;
    int flag = (t == 0) || (midx[b * 1024 + t] == 0);
    int v = flag ? t : -1;
    sb[t] = v;
    __syncthreads();
    for (int off = 1; off < 1024; off <<= 1) {
        int u = (t >= off) ? sb[t - off] : -1;
        __syncthreads();
        if (u > v) v = u;
        sb[t] = v;
        __syncthreads();
    }
    rsel[b * 1024 + t] = v;
}

// ---------------------------------------------------------------- output writer
__global__ __launch_bounds__(256) void writer_kernel(
    const float* __restrict__ klog, const float* __restrict__ mlog,
    const int* __restrict__ kidx, const int* __restrict__ midx,
    const int* __restrict__ rsel, float* __restrict__ out)
{
    int lane = threadIdx.x & 63;
    int p = blockIdx.x * 4 + (threadIdx.x >> 6);
    int b = p >> 10, t = p & 1023;

    float kl = (lane < NK) ? klog[(size_t)p * NK + lane] : -INFINITY;
    float mx = kl;
#pragma unroll
    for (int off = 1; off < 64; off <<= 1) mx = fmaxf(mx, __shfl_xor(mx, off));
    float e = (lane < NK) ? expf(kl - mx) : 0.f;
    float ssum = e;
#pragma unroll
    for (int off = 1; off < 64; off <<= 1) ssum += __shfl_xor(ssum, off);
    float soft = e / ssum;

    float z0 = mlog[(size_t)p * 2], z1 = mlog[(size_t)p * 2 + 1];
    float mmx = fmaxf(z0, z1);
    float e0 = expf(z0 - mmx), e1 = expf(z1 - mmx);
    float mp0 = e0 / (e0 + e1), mp1 = e1 / (e0 + e1);

    int r = rsel[p];
    int kc = kidx[b * 1024 + r];
    int hasprev = (t > 0);
    int kp = 0;
    if (hasprev) { int rp = rsel[p - 1]; kp = kidx[b * 1024 + rp]; }

    if (lane < NK) {
        out[OFF_SK + (size_t)p * NK + lane] = (lane == kc) ? 1.f : 0.f;
        float skl = (hasprev && lane == kp) ? 1.f : 0.f;
        out[OFF_KP + (size_t)p * NK + lane] = skl * mp1 + soft * mp0;
    }
    if (lane == 0) {
        int ms0 = (t == 0) ? 1 : ((midx[p] == 0) ? 1 : 0);
        out[OFF_MS + (size_t)p * 2]     = (float)ms0;
        out[OFF_MS + (size_t)p * 2 + 1] = (float)(1 - ms0);
        out[OFF_MP + (size_t)p * 2]     = mp0;
        out[OFF_MP + (size_t)p * 2 + 1] = mp1;
    }
}

// ---------------------------------------------------------------- host
extern "C" void kernel_launch(void* const* d_in, const int* in_sizes, int n_in,
                              void* d_out, int out_size, void* d_ws, size_t ws_size,
                              hipStream_t stream)
{
    (void)in_sizes; (void)n_in; (void)out_size; (void)ws_size;
    const float* state  = (const float*)d_in[0];
    const float* act    = (const float*)d_in[1];
    const float* goal   = (const float*)d_in[2];
    const float* u_m    = (const float*)d_in[4];
    const float* u_k    = (const float*)d_in[5];
    const float* W_in   = (const float*)d_in[6];
    const float* b_in   = (const float*)d_in[7];
    const float* Wqkv   = (const float*)d_in[8];
    const float* bqkv   = (const float*)d_in[9];
    const float* Wo     = (const float*)d_in[10];
    const float* bo     = (const float*)d_in[11];
    const float* ln1_g  = (const float*)d_in[12];
    const float* ln1_b  = (const float*)d_in[13];
    const float* W1     = (const float*)d_in[14];
    const float* b1     = (const float*)d_in[15];
    const float* W2     = (const float*)d_in[16];
    const float* b2     = (const float*)d_in[17];
    const float* ln2_g  = (const float*)d_in[18];
    const float* ln2_b  = (const float*)d_in[19];
    const float* W_out  = (const float*)d_in[20];
    const float* b_out  = (const float*)d_in[21];
    const float* W_k1   = (const float*)d_in[22];
    const float* b_k1   = (const float*)d_in[23];
    const float* W_sub  = (const float*)d_in[24];
    const float* b_sub  = (const float*)d_in[25];
    const float* W_term = (const float*)d_in[26];
    const float* b_term = (const float*)d_in[27];

    char* wsb = (char*)d_ws;
    float* x   = (float*)(wsb);                               // 32 MiB
    float* x2  = (float*)(wsb + 33554432);                    // 32 MiB
    float* big = (float*)(wsb + 67108864);                    // 128 MiB
    char*  apl = wsb + 201326592;                             // 40 MiB act planes
    char*  wpl = wsb + 243269632;                             // 16 MiB weight planes
    char*  tail = wsb + 260046848;
    int* kidx = (int*)tail;
    int* midx = (int*)(tail + 65536);
    int* rsel = (int*)(tail + 131072);

    _Float16* APh = (_Float16*)apl;
    float* out128 = big;
    float* hid128 = (float*)((char*)big + 8388608);
    float* klog   = (float*)((char*)big + 16777216);
    float* mlog   = (float*)((char*)big + 20054016);
    float* bigmid = big;                                      // 4096x2048 f32 chunk
    _Float16* CPh = (_Float16*)((char*)big + 33554432);       // chunk planes
    _Float16* CPl = CPh + 4096 * 2048;

    // ---- input concat + embed
    concat_kernel<<<9216, 256, 0, stream>>>(state, act, goal, big);
    {   // feats planes (E = 16384*576)
        _Float16* fl = APh + (size_t)T_TOT * DIN;
        conv_act<<<dim3(DIN / 32, T_TOT / 256), 256, 0, stream>>>(big, DIN, APh, fl, T_TOT);
        _Float16* wh = (_Float16*)wpl; _Float16* wl = wh + DIN * DM;
        conv_w<<<dim3(DM / 128, DIN / 32), 256, 0, stream>>>(W_in, DM, wh, wl);
        gemm_mfma<<<dim3(DM / 128, T_TOT / 128), 256, 0, stream>>>(
            APh, fl, wh, wl, b_in, x, DM, T_TOT, DM, DIN, 0, 0, 0);
    }

    _Float16* APl512 = APh + (size_t)T_TOT * DM;

    for (int l = 0; l < 3; ++l) {
        // weight planes for this layer
        _Float16* qh = (_Float16*)wpl;            _Float16* ql  = qh + DM * 3 * DM;
        _Float16* oh = ql + DM * 3 * DM;          _Float16* ol  = oh + DM * DM;
        _Float16* w1h = ol + DM * DM;             _Float16* w1l = w1h + DM * DFF;
        _Float16* w2h = w1l + DM * DFF;           _Float16* w2l = w2h + DFF * DM;
        conv_w<<<dim3(3 * DM / 128, DM / 32), 256, 0, stream>>>(Wqkv + (size_t)l * DM * 3 * DM, 3 * DM, qh, ql);
        conv_w<<<dim3(DM / 128, DM / 32), 256, 0, stream>>>(Wo + (size_t)l * DM * DM, DM, oh, ol);
        conv_w<<<dim3(DFF / 128, DM / 32), 256, 0, stream>>>(W1 + (size_t)l * DM * DFF, DFF, w1h, w1l);
        conv_w<<<dim3(DM / 128, DFF / 32), 256, 0, stream>>>(W2 + (size_t)l * DFF * DM, DM, w2h, w2l);

        // qkv
        conv_act<<<dim3(DM / 32, T_TOT / 256), 256, 0, stream>>>(x, DM, APh, APl512, T_TOT);
        gemm_mfma<<<dim3(3 * DM / 128, T_TOT / 128), 256, 0, stream>>>(
            APh, APl512, qh, ql, bqkv + (size_t)l * 3 * DM, big, 2048, T_TOT, 3 * DM, DM, 0, 0, 0);
        attn_f32<<<dim3(16, NHEAD, B_SZ), 256, 0, stream>>>(big, big + 1536);
        // Wo
        conv_act<<<dim3(DM / 32, T_TOT / 256), 256, 0, stream>>>(big + 1536, 2048, APh, APl512, T_TOT);
        gemm_mfma<<<dim3(DM / 128, T_TOT / 128), 256, 0, stream>>>(
            APh, APl512, oh, ol, bo + (size_t)l * DM, x2, DM, T_TOT, DM, DM, 0, 0, 0);
        add_ln<<<T_TOT, 256, 0, stream>>>(x, x2, ln1_g + (size_t)l * DM, ln1_b + (size_t)l * DM, x2);
        // FFN in 4 row-chunks of 4096
        conv_act<<<dim3(DM / 32, T_TOT / 256), 256, 0, stream>>>(x2, DM, APh, APl512, T_TOT);
        for (int c = 0; c < 4; ++c) {
            gemm_mfma<<<dim3(DFF / 128, 32), 256, 0, stream>>>(
                APh, APl512, w1h, w1l, b1 + (size_t)l * DFF, bigmid, DFF,
                T_TOT, DFF, DM, 1, c * 32, c * 4096);
            conv_act<<<dim3(DFF / 32, 4096 / 256), 256, 0, stream>>>(bigmid, DFF, CPh, CPl, 4096);
            gemm_mfma<<<dim3(DM / 128, 32), 256, 0, stream>>>(
                CPh, CPl, w2h, w2l, b2 + (size_t)l * DM, x + (size_t)c * 4096 * DM, DM,
                4096, DM, DFF, 0, 0, 0);
        }
        add_ln<<<T_TOT, 256, 0, stream>>>(x2, x, ln2_g + (size_t)l * DM, ln2_b + (size_t)l * DM, x);
    }

    // ---- heads
    conv_act<<<dim3(DM / 32, T_TOT / 256), 256, 0, stream>>>(x, DM, APh, APl512, T_TOT);
    {
        _Float16* wh = (_Float16*)wpl; _Float16* wl = wh + DM * 128;
        conv_w<<<dim3(1, DM / 32), 256, 0, stream>>>(W_out, 128, wh, wl);
        gemm_mfma<<<dim3(1, T_TOT / 128), 256, 0, stream>>>(
            APh, APl512, wh, wl, b_out, out128, 128, T_TOT, 128, DM, 0, 0, 0);
    }
    {
        _Float16* al = APh + (size_t)T_TOT * 128;
        conv_act<<<dim3(128 / 32, T_TOT / 256), 256, 0, stream>>>(out128, 128, APh, al, T_TOT);
        _Float16* wh = (_Float16*)wpl; _Float16* wl = wh + 128 * 128;
        conv_w<<<dim3(1, 128 / 32), 256, 0, stream>>>(W_k1, 128, wh, wl);
        gemm_mfma<<<dim3(1, T_TOT / 128), 256, 0, stream>>>(
            APh, al, wh, wl, b_k1, hid128, 128, T_TOT, 128, 128, 1, 0, 0);
    }
    gemm_f32<<<dim3(1, T_TOT / 128), 256, 0, stream>>>(hid128, 128, W_sub, b_sub, klog, NK, T_TOT, 128, NK, 0);
    gemm_f32<<<dim3(1, T_TOT / 128), 256, 0, stream>>>(out128, 128, W_term, b_term, mlog, 2, T_TOT, 128, 2, 0);

    gumbel_k_kernel<<<T_TOT / 4, 256, 0, stream>>>(klog, u_k, kidx);
    gumbel_m_kernel<<<T_TOT / 256, 256, 0, stream>>>(mlog, u_m, midx);
    scan_kernel<<<B_SZ, 1024, 0, stream>>>(midx, rsel);
    writer_kernel<<<T_TOT / 4, 256, 0, stream>>>(klog, mlog, kidx, midx, rsel, (float*)d_out);
}

// Round 6
// 2674.788 us; speedup vs baseline: 3.0336x; 3.0336x over previous
//
#include <hip/hip_runtime.h>
#include <math.h>

#define T_TOT  16384     // B*S
#define S_LEN  1024
#define B_SZ   16
#define DM     512
#define DIN    576
#define DFF    2048
#define NHEAD  8
#define DHEAD  64
#define NK     50

#define OFF_SK 0
#define OFF_MS 819200
#define OFF_KP 851968
#define OFF_MP 1671168

#define MB (1024*1024)

typedef _Float16 half8 __attribute__((ext_vector_type(8)));
typedef float floatx4 __attribute__((ext_vector_type(4)));

__device__ __forceinline__ void glds16(const _Float16* g, _Float16* l) {
    __builtin_amdgcn_global_load_lds(
        (const __attribute__((address_space(1))) void*)g,
        (__attribute__((address_space(3))) void*)l, 16, 0, 0);
}
__device__ __forceinline__ unsigned short h2u(_Float16 h) { return __builtin_bit_cast(unsigned short, h); }
__device__ __forceinline__ _Float16 u2h(unsigned short u) { return __builtin_bit_cast(_Float16, u); }

// ---------------------------------------------------------------- concat
__global__ __launch_bounds__(256) void concat_kernel(
    const float* __restrict__ st, const float* __restrict__ ac,
    const float* __restrict__ go, float* __restrict__ out)
{
    int idx = blockIdx.x * 256 + threadIdx.x;            // float4 id
    int row = idx / 144;                                 // DIN/4 = 144
    int c4  = idx - row * 144;
    float4 v;
    if (c4 < 64)      v = ((const float4*)st)[(size_t)row * 64 + c4];
    else if (c4 < 80) v = ((const float4*)ac)[(size_t)row * 16 + (c4 - 64)];
    else              v = ((const float4*)go)[(size_t)row * 64 + (c4 - 80)];
    ((float4*)out)[idx] = v;
}

// ---------------------------------------------------------------- conv act f32 -> f16 hi/lo planes (A-fragment order)
// chunk(sm,sk) base ((sk*(M>>4)+sm)*64+lane)*8, lane=(row&15)+((k>>3)&3)*16, j=k&7
__global__ __launch_bounds__(256) void conv_act(
    const float* __restrict__ A, int lda,
    _Float16* __restrict__ Ph, _Float16* __restrict__ Pl, int M)
{
    __shared__ _Float16 lh[16 * 512];
    __shared__ _Float16 ll[16 * 512];
    const int tid = threadIdx.x;
    const int sk = blockIdx.x;
    const int m0 = blockIdx.y * 256;
    const int SM = M >> 4;
#pragma unroll
    for (int i = 0; i < 8; ++i) {
        int idx = tid + i * 256;               // 2048 float4
        int rl = idx >> 3, kq = idx & 7;
        float4 f = *(const float4*)&A[(size_t)(m0 + rl) * lda + sk * 32 + kq * 4];
        int lane = (rl & 15) + (kq >> 1) * 16;
        int off = ((rl >> 4) * 64 + lane) * 8 + (kq & 1) * 4;
        _Float16 h0 = (_Float16)f.x, h1 = (_Float16)f.y, h2 = (_Float16)f.z, h3 = (_Float16)f.w;
        lh[off + 0] = h0; lh[off + 1] = h1; lh[off + 2] = h2; lh[off + 3] = h3;
        ll[off + 0] = (_Float16)((f.x - (float)h0) * 2048.f);
        ll[off + 1] = (_Float16)((f.y - (float)h1) * 2048.f);
        ll[off + 2] = (_Float16)((f.z - (float)h2) * 2048.f);
        ll[off + 3] = (_Float16)((f.w - (float)h3) * 2048.f);
    }
    __syncthreads();
#pragma unroll
    for (int i = 0; i < 8; ++i) {
        int idx = tid + i * 256;               // 2048 16B-chunks
        int plane = idx >> 10, q = idx & 1023;
        int s = q >> 6, ln = q & 63;
        uint4 v = *(const uint4*)&(plane ? ll : lh)[(s * 64 + ln) * 8];
        _Float16* P = plane ? Pl : Ph;
        *(uint4*)&P[((size_t)(sk * SM + (m0 >> 4) + s) * 64 + ln) * 8] = v;
    }
}

// ---------------------------------------------------------------- conv weight f32 [K,N] -> B-fragment planes
__global__ __launch_bounds__(256) void conv_w(
    const float* __restrict__ W, int N,
    _Float16* __restrict__ Ph, _Float16* __restrict__ Pl)
{
    __shared__ _Float16 lh[8 * 512];
    __shared__ _Float16 ll[8 * 512];
    const int tid = threadIdx.x;
    const int sk = blockIdx.y;
    const int n0 = blockIdx.x * 128;
    const int SN = N >> 4;
#pragma unroll
    for (int i = 0; i < 4; ++i) {
        int idx = tid + i * 256;               // 1024 float4
        int k = idx >> 5, n4 = idx & 31;
        float4 f = *(const float4*)&W[(size_t)(sk * 32 + k) * N + n0 + n4 * 4];
        int kb = (k >> 3) & 3, j = k & 7;
        float vv[4] = {f.x, f.y, f.z, f.w};
#pragma unroll
        for (int t = 0; t < 4; ++t) {
            int nl = n4 * 4 + t;
            int off = ((nl >> 4) * 64 + (nl & 15) + kb * 16) * 8 + j;
            _Float16 h = (_Float16)vv[t];
            lh[off] = h;
            ll[off] = (_Float16)((vv[t] - (float)h) * 2048.f);
        }
    }
    __syncthreads();
#pragma unroll
    for (int i = 0; i < 4; ++i) {
        int idx = tid + i * 256;               // 1024 chunks
        int plane = idx >> 9, q = idx & 511;
        int s = q >> 6, ln = q & 63;
        uint4 v = *(const uint4*)&(plane ? ll : lh)[(s * 64 + ln) * 8];
        _Float16* P = plane ? Pl : Ph;
        *(uint4*)&P[((size_t)(sk * SN + (n0 >> 4) + s) * 64 + ln) * 8] = v;
    }
}

// ---------------------------------------------------------------- split-f16 MFMA GEMM (global_load_lds staging)
__global__ __launch_bounds__(256, 2) void gemm_mfma(
    const _Float16* __restrict__ Ah, const _Float16* __restrict__ Al,
    const _Float16* __restrict__ Bh, const _Float16* __restrict__ Bl,
    const float* __restrict__ bias, float* __restrict__ C, int ldc,
    int M, int N, int K, int relu, int mb0, int mrow_sub)
{
    __shared__ _Float16 ldsf[16384];   // 32KB: [Ah|Al|Bh|Bl] x 8 chunks x 512
    const int tid = threadIdx.x;
    const int lane = tid & 63, wave = tid >> 6;
    const int wm = wave >> 1, wn = wave & 1;
    const int m0 = (blockIdx.y + mb0) * 128;
    const int n0 = blockIdx.x * 128;
    const int SM = M >> 4, SN = N >> 4;
    const int sm0 = m0 >> 4, sn0 = n0 >> 4;

    floatx4 accM[4][4], accC[4][4];
#pragma unroll
    for (int i = 0; i < 4; ++i)
#pragma unroll
        for (int j = 0; j < 4; ++j) {
            accM[i][j] = floatx4{0.f, 0.f, 0.f, 0.f};
            accC[i][j] = floatx4{0.f, 0.f, 0.f, 0.f};
        }

    const int nkt = K >> 5;
    const int abase = (wm * 4 * 64 + lane) * 8;
    const int bbase = 8192 + (wn * 4 * 64 + lane) * 8;
    const int s4 = wave;      // chunk-within-region selector
    for (int kt = 0; kt < nkt; ++kt) {
#pragma unroll
        for (int i = 0; i < 8; ++i) {
            int s = (i & 1) * 4 + s4;
            const _Float16* P = (i < 2) ? Ah : (i < 4) ? Al : (i < 6) ? Bh : Bl;
            size_t chunk = (i < 4) ? ((size_t)kt * SM + sm0 + s)
                                   : ((size_t)kt * SN + sn0 + s);
            glds16(&P[(chunk * 64 + lane) * 8], &ldsf[(i * 256 + wave * 64) * 8]);
        }
        __syncthreads();
        half8 a_h[4], a_l[4];
#pragma unroll
        for (int mi = 0; mi < 4; ++mi) {
            a_h[mi] = *(const half8*)&ldsf[abase + mi * 512];
            a_l[mi] = *(const half8*)&ldsf[abase + 4096 + mi * 512];
        }
#pragma unroll
        for (int ni = 0; ni < 4; ++ni) {
            half8 b_h = *(const half8*)&ldsf[bbase + ni * 512];
            half8 b_l = *(const half8*)&ldsf[bbase + 4096 + ni * 512];
#pragma unroll
            for (int mi = 0; mi < 4; ++mi) {
                accM[mi][ni] = __builtin_amdgcn_mfma_f32_16x16x32_f16(a_h[mi], b_h, accM[mi][ni], 0, 0, 0);
                accC[mi][ni] = __builtin_amdgcn_mfma_f32_16x16x32_f16(a_l[mi], b_h, accC[mi][ni], 0, 0, 0);
                accC[mi][ni] = __builtin_amdgcn_mfma_f32_16x16x32_f16(a_h[mi], b_l, accC[mi][ni], 0, 0, 0);
            }
        }
        __syncthreads();
    }

    const int colq = lane & 15, rq = lane >> 4;
#pragma unroll
    for (int ni = 0; ni < 4; ++ni) {
        int col = n0 + wn * 64 + ni * 16 + colq;
        float bv = bias[col];
#pragma unroll
        for (int mi = 0; mi < 4; ++mi) {
            floatx4 d = accM[mi][ni] + accC[mi][ni] * (1.0f / 2048.0f);
            int row0 = m0 - mrow_sub + wm * 64 + mi * 16 + rq * 4;
#pragma unroll
            for (int r = 0; r < 4; ++r) {
                float v = d[r] + bv;
                if (relu) v = fmaxf(v, 0.f);
                C[(size_t)(row0 + r) * ldc + col] = v;
            }
        }
    }
}

// ---------------------------------------------------------------- qkv f32 -> attention split-f16 fragment planes
// Q/K: A-style per (b,h): chunk(t16,dblk) idx=t16*2+dblk, lane=(t&15)+((d>>3)&3)*16, j=d&7
// V:   B-style per (b,h): chunk(t32,d16) idx=t32*4+d16, lane=(d&15)+((t>>3)&3)*16, j=t&7
__global__ __launch_bounds__(256) void conv_qkv(
    const float* __restrict__ qkv,
    _Float16* __restrict__ QH, _Float16* __restrict__ QL,
    _Float16* __restrict__ KH, _Float16* __restrict__ KL,
    _Float16* __restrict__ VH, _Float16* __restrict__ VL)
{
    const int tid = threadIdx.x;
    const int tt = blockIdx.x, h = blockIdx.y, b = blockIdx.z;
    const int bh = b * 8 + h;
    const size_t pb = (size_t)bh * 65536;   // halves per (b,h) per plane
#pragma unroll
    for (int m = 0; m < 2; ++m) {           // 0=Q, 1=K
        int colb = h * 64 + m * 512;
        _Float16* PH = m ? KH : QH;
        _Float16* PL = m ? KL : QL;
#pragma unroll
        for (int it = 0; it < 2; ++it) {
            int idx = tid + it * 256;        // 512 lane-slots
            int c = idx >> 6, ln = idx & 63;
            int t16r = c >> 1, dblk = c & 1;
            int t = tt * 64 + t16r * 16 + (ln & 15);
            int d0 = dblk * 32 + (ln >> 4) * 8;
            const float* src = qkv + (size_t)(b * 1024 + t) * 1536 + colb + d0;
            float4 f0 = *(const float4*)src;
            float4 f1 = *(const float4*)(src + 4);
            float v[8] = {f0.x, f0.y, f0.z, f0.w, f1.x, f1.y, f1.z, f1.w};
            half8 hv, lv;
#pragma unroll
            for (int j = 0; j < 8; ++j) {
                _Float16 hh = (_Float16)v[j];
                hv[j] = hh;
                lv[j] = (_Float16)((v[j] - (float)hh) * 2048.f);
            }
            size_t off = pb + ((size_t)(tt * 4 + t16r) * 2 + dblk) * 512 + ln * 8;
            *(half8*)&PH[off] = hv;
            *(half8*)&PL[off] = lv;
        }
    }
#pragma unroll
    for (int it = 0; it < 2; ++it) {         // V
        int idx = tid + it * 256;
        int c = idx >> 6, ln = idx & 63;
        int kb = c >> 2, d16 = c & 3;
        int d = d16 * 16 + (ln & 15);
        int t0 = tt * 64 + kb * 32 + ((ln >> 4) & 3) * 8;
        half8 hv, lv;
#pragma unroll
        for (int j = 0; j < 8; ++j) {
            float v = qkv[(size_t)(b * 1024 + t0 + j) * 1536 + 1024 + h * 64 + d];
            _Float16 hh = (_Float16)v;
            hv[j] = hh;
            lv[j] = (_Float16)((v - (float)hh) * 2048.f);
        }
        size_t off = pb + ((size_t)(tt * 2 + kb) * 4 + d16) * 512 + ln * 8;
        *(half8*)&VH[off] = hv;
        *(half8*)&VL[off] = lv;
    }
}

// ---------------------------------------------------------------- split-f16 MFMA flash attention (causal)
__global__ __launch_bounds__(256) void attn_mfma(
    const _Float16* __restrict__ QH, const _Float16* __restrict__ QL,
    const _Float16* __restrict__ KH, const _Float16* __restrict__ KL,
    const _Float16* __restrict__ VH, const _Float16* __restrict__ VL,
    float* __restrict__ out)
{
    __shared__ _Float16 kh_s[4096], kl_s[4096], vh_s[4096], vl_s[4096];
    __shared__ unsigned int p_s[64 * 68];
    const int tid = threadIdx.x;
    const int l = tid & 63, w = tid >> 6;
    const int qi = blockIdx.x, h = blockIdx.y, b = blockIdx.z;
    const int bh = b * 8 + h;
    const size_t pb = (size_t)bh * 65536;

    half8 qh[2], ql[2];
#pragma unroll
    for (int dblk = 0; dblk < 2; ++dblk) {
        size_t off = pb + ((size_t)(qi * 4 + w) * 2 + dblk) * 512 + l * 8;
        qh[dblk] = *(const half8*)&QH[off];
        ql[dblk] = *(const half8*)&QL[off];
    }

    floatx4 oM[4], oC[4];
#pragma unroll
    for (int s = 0; s < 4; ++s) {
        oM[s] = floatx4{0.f, 0.f, 0.f, 0.f};
        oC[s] = floatx4{0.f, 0.f, 0.f, 0.f};
    }
    float mrun[4], lrun[4];
#pragma unroll
    for (int r = 0; r < 4; ++r) { mrun[r] = -INFINITY; lrun[r] = 0.f; }

    for (int kt = 0; kt <= qi; ++kt) {
#pragma unroll
        for (int i = 0; i < 2; ++i) {          // stage K/V tile (32KB)
            int ci = w * 2 + i;
            size_t goff = pb + (size_t)(kt * 8 + ci) * 512 + l * 8;
            int loff = ci * 512;
            glds16(&KH[goff], &kh_s[loff]);
            glds16(&KL[goff], &kl_s[loff]);
            glds16(&VH[goff], &vh_s[loff]);
            glds16(&VL[goff], &vl_s[loff]);
        }
        __syncthreads();

        // S = Q K^T  (dual accumulator)
        float p[4][4];
#pragma unroll
        for (int sub = 0; sub < 4; ++sub) {
            half8 k0h = *(const half8*)&kh_s[(sub * 2 + 0) * 512 + l * 8];
            half8 k1h = *(const half8*)&kh_s[(sub * 2 + 1) * 512 + l * 8];
            half8 k0l = *(const half8*)&kl_s[(sub * 2 + 0) * 512 + l * 8];
            half8 k1l = *(const half8*)&kl_s[(sub * 2 + 1) * 512 + l * 8];
            floatx4 aM = floatx4{0.f, 0.f, 0.f, 0.f};
            floatx4 aC = floatx4{0.f, 0.f, 0.f, 0.f};
            aM = __builtin_amdgcn_mfma_f32_16x16x32_f16(qh[0], k0h, aM, 0, 0, 0);
            aM = __builtin_amdgcn_mfma_f32_16x16x32_f16(qh[1], k1h, aM, 0, 0, 0);
            aC = __builtin_amdgcn_mfma_f32_16x16x32_f16(ql[0], k0h, aC, 0, 0, 0);
            aC = __builtin_amdgcn_mfma_f32_16x16x32_f16(ql[1], k1h, aC, 0, 0, 0);
            aC = __builtin_amdgcn_mfma_f32_16x16x32_f16(qh[0], k0l, aC, 0, 0, 0);
            aC = __builtin_amdgcn_mfma_f32_16x16x32_f16(qh[1], k1l, aC, 0, 0, 0);
            floatx4 sv = aM + aC * (1.0f / 2048.0f);
#pragma unroll
            for (int r = 0; r < 4; ++r) p[sub][r] = sv[r] * 0.125f;
        }
        if (kt == qi) {                        // causal mask on diag tile
#pragma unroll
            for (int sub = 0; sub < 4; ++sub)
#pragma unroll
                for (int r = 0; r < 4; ++r) {
                    int col = sub * 16 + (l & 15);
                    int row = w * 16 + (l >> 4) * 4 + r;
                    if (col > row) p[sub][r] = -1e9f;
                }
        }
        // online softmax (rows live in 16-lane groups: xor 1,2,4,8)
        float tmax[4], ls[4], scl[4];
#pragma unroll
        for (int r = 0; r < 4; ++r) {
            float tm = fmaxf(fmaxf(p[0][r], p[1][r]), fmaxf(p[2][r], p[3][r]));
            tm = fmaxf(tm, __shfl_xor(tm, 1));
            tm = fmaxf(tm, __shfl_xor(tm, 2));
            tm = fmaxf(tm, __shfl_xor(tm, 4));
            tm = fmaxf(tm, __shfl_xor(tm, 8));
            tmax[r] = tm;
            float mn = fmaxf(mrun[r], tm);
            scl[r] = expf(mrun[r] - mn);
            mrun[r] = mn;
            ls[r] = 0.f;
        }
#pragma unroll
        for (int sub = 0; sub < 4; ++sub)
#pragma unroll
            for (int r = 0; r < 4; ++r) {
                float e = expf(p[sub][r] - mrun[r]);
                p[sub][r] = e;
                ls[r] += e;
            }
#pragma unroll
        for (int r = 0; r < 4; ++r) {
            float s = ls[r];
            s += __shfl_xor(s, 1);
            s += __shfl_xor(s, 2);
            s += __shfl_xor(s, 4);
            s += __shfl_xor(s, 8);
            lrun[r] = lrun[r] * scl[r] + s;
        }
#pragma unroll
        for (int sub = 0; sub < 4; ++sub)
#pragma unroll
            for (int r = 0; r < 4; ++r) { oM[sub][r] *= scl[r]; oC[sub][r] *= scl[r]; }
        // write P (packed hi|lo f16) to LDS
#pragma unroll
        for (int sub = 0; sub < 4; ++sub)
#pragma unroll
            for (int r = 0; r < 4; ++r) {
                float e = p[sub][r];
                _Float16 eh = (_Float16)e;
                _Float16 el = (_Float16)((e - (float)eh) * 2048.f);
                unsigned int u = (unsigned int)h2u(eh) | ((unsigned int)h2u(el) << 16);
                p_s[(w * 16 + (l >> 4) * 4 + r) * 68 + sub * 16 + (l & 15)] = u;
            }
        __syncthreads();

        // O += P V
#pragma unroll
        for (int kb = 0; kb < 2; ++kb) {
            const unsigned int* pr = &p_s[(w * 16 + (l & 15)) * 68 + kb * 32 + (l >> 4) * 8];
            unsigned int pu[8];
            *(uint4*)&pu[0] = *(const uint4*)pr;
            *(uint4*)&pu[4] = *(const uint4*)(pr + 4);
            half8 pah, pal;
#pragma unroll
            for (int j = 0; j < 8; ++j) {
                pah[j] = u2h((unsigned short)(pu[j] & 0xffffu));
                pal[j] = u2h((unsigned short)(pu[j] >> 16));
            }
#pragma unroll
            for (int sub = 0; sub < 4; ++sub) {
                half8 vh = *(const half8*)&vh_s[(kb * 4 + sub) * 512 + l * 8];
                half8 vl = *(const half8*)&vl_s[(kb * 4 + sub) * 512 + l * 8];
                oM[sub] = __builtin_amdgcn_mfma_f32_16x16x32_f16(pah, vh, oM[sub], 0, 0, 0);
                oC[sub] = __builtin_amdgcn_mfma_f32_16x16x32_f16(pal, vh, oC[sub], 0, 0, 0);
                oC[sub] = __builtin_amdgcn_mfma_f32_16x16x32_f16(pah, vl, oC[sub], 0, 0, 0);
            }
        }
        __syncthreads();
    }

#pragma unroll
    for (int sub = 0; sub < 4; ++sub)
#pragma unroll
        for (int r = 0; r < 4; ++r) {
            float v = (oM[sub][r] + oC[sub][r] * (1.0f / 2048.0f)) / lrun[r];
            out[(size_t)(b * 1024 + qi * 64 + w * 16 + (l >> 4) * 4 + r) * 512
                + h * 64 + sub * 16 + (l & 15)] = v;
        }
}

// ---------------------------------------------------------------- GEMM f32 (small heads: N=50, N=2)
__global__ __launch_bounds__(256) void gemm_f32(
    const float* __restrict__ A, int lda,
    const float* __restrict__ W, const float* __restrict__ bias,
    float* __restrict__ C, int ldc, int M, int K, int N, int relu)
{
    __shared__ float As[16][128];
    __shared__ float Bs[16][128];
    const int tid = threadIdx.x;
    const int tx = tid & 15, ty = tid >> 4;
    const int m0 = blockIdx.y * 128;
    const int n0 = blockIdx.x * 128;
    const bool nfull = (n0 + 128 <= N) && ((N & 3) == 0);

    float acc[8][8];
#pragma unroll
    for (int i = 0; i < 8; ++i)
#pragma unroll
        for (int j = 0; j < 8; ++j) acc[i][j] = 0.f;

    const int nkt = K >> 4;
    for (int kt = 0; kt < nkt; ++kt) {
#pragma unroll
        for (int i = 0; i < 2; ++i) {
            int q = tid * 2 + i;
            int r = q >> 2, c = (q & 3) * 4;
            float4 v = *(const float4*)(A + (size_t)(m0 + r) * lda + kt * 16 + c);
            As[c + 0][r] = v.x; As[c + 1][r] = v.y;
            As[c + 2][r] = v.z; As[c + 3][r] = v.w;
        }
#pragma unroll
        for (int i = 0; i < 2; ++i) {
            int q = tid * 2 + i;
            int kr = q >> 5, c = (q & 31) * 4;
            const float* wr = W + (size_t)(kt * 16 + kr) * N;
            int col = n0 + c;
            float4 v;
            if (nfull) v = *(const float4*)(wr + col);
            else {
                v.x = (col     < N) ? wr[col]     : 0.f;
                v.y = (col + 1 < N) ? wr[col + 1] : 0.f;
                v.z = (col + 2 < N) ? wr[col + 2] : 0.f;
                v.w = (col + 3 < N) ? wr[col + 3] : 0.f;
            }
            *(float4*)&Bs[kr][c] = v;
        }
        __syncthreads();
#pragma unroll
        for (int kk = 0; kk < 16; ++kk) {
            float a[8], bb[8];
            *(float4*)&a[0]  = *(const float4*)&As[kk][ty * 8];
            *(float4*)&a[4]  = *(const float4*)&As[kk][ty * 8 + 4];
            *(float4*)&bb[0] = *(const float4*)&Bs[kk][tx * 8];
            *(float4*)&bb[4] = *(const float4*)&Bs[kk][tx * 8 + 4];
#pragma unroll
            for (int i = 0; i < 8; ++i)
#pragma unroll
                for (int j = 0; j < 8; ++j)
                    acc[i][j] = fmaf(a[i], bb[j], acc[i][j]);
        }
        __syncthreads();
    }

    float bv[8];
#pragma unroll
    for (int j = 0; j < 8; ++j) {
        int col = n0 + tx * 8 + j;
        bv[j] = (col < N) ? bias[col] : 0.f;
    }
#pragma unroll
    for (int i = 0; i < 8; ++i) {
        int row = m0 + ty * 8 + i;
#pragma unroll
        for (int j = 0; j < 8; ++j) {
            int col = n0 + tx * 8 + j;
            if (col < N) {
                float v = acc[i][j] + bv[j];
                if (relu) v = fmaxf(v, 0.f);
                C[(size_t)row * ldc + col] = v;
            }
        }
    }
}

// ---------------------------------------------------------------- residual + LayerNorm
__global__ __launch_bounds__(256) void add_ln(
    const float* __restrict__ xin, const float* __restrict__ res,
    const float* __restrict__ gg, const float* __restrict__ bb,
    float* __restrict__ yout)
{
    int row = blockIdx.x, tid = threadIdx.x;
    __shared__ float red[8];
    size_t base = (size_t)row * DM + tid * 2;
    float2 u = *(const float2*)&xin[base];
    float2 v = *(const float2*)&res[base];
    float a = u.x + v.x, c = u.y + v.y;
    float s = a + c;
#pragma unroll
    for (int off = 32; off; off >>= 1) s += __shfl_xor(s, off);
    int wid = tid >> 6, lane = tid & 63;
    if (lane == 0) red[wid] = s;
    __syncthreads();
    float mu = (red[0] + red[1] + red[2] + red[3]) * (1.0f / 512.0f);
    float da = a - mu, dc = c - mu;
    float vs = da * da + dc * dc;
#pragma unroll
    for (int off = 32; off; off >>= 1) vs += __shfl_xor(vs, off);
    if (lane == 0) red[4 + wid] = vs;
    __syncthreads();
    float var = (red[4] + red[5] + red[6] + red[7]) * (1.0f / 512.0f);
    float rs = 1.0f / sqrtf(var + 1e-5f);
    float2 oo;
    oo.x = da * rs * gg[tid * 2]     + bb[tid * 2];
    oo.y = dc * rs * gg[tid * 2 + 1] + bb[tid * 2 + 1];
    *(float2*)&yout[base] = oo;
}

// ---------------------------------------------------------------- gumbel argmax (k, 50-way)
__global__ __launch_bounds__(256) void gumbel_k_kernel(
    const float* __restrict__ klog, const float* __restrict__ uk,
    int* __restrict__ kidx)
{
    int lane = threadIdx.x & 63;
    int p = blockIdx.x * 4 + (threadIdx.x >> 6);
    float z = -INFINITY;
    if (lane < NK) {
        float u = uk[(size_t)p * NK + lane];
        float g = -logf(-logf(u + 1e-10f) + 1e-10f);
        z = klog[(size_t)p * NK + lane] + g;
    }
    int idx = lane;
#pragma unroll
    for (int off = 1; off < 64; off <<= 1) {
        float oz = __shfl_xor(z, off);
        int   oi = __shfl_xor(idx, off);
        if (oz > z || (oz == z && oi < idx)) { z = oz; idx = oi; }
    }
    if (lane == 0) kidx[p] = idx;
}

// ---------------------------------------------------------------- gumbel argmax (m, 2-way)
__global__ __launch_bounds__(256) void gumbel_m_kernel(
    const float* __restrict__ mlog, const float* __restrict__ um,
    int* __restrict__ midx)
{
    int p = blockIdx.x * 256 + threadIdx.x;
    if (p >= T_TOT) return;
    float u0 = um[(size_t)p * 2], u1 = um[(size_t)p * 2 + 1];
    float g0 = -logf(-logf(u0 + 1e-10f) + 1e-10f);
    float g1 = -logf(-logf(u1 + 1e-10f) + 1e-10f);
    float z0 = mlog[(size_t)p * 2] + g0, z1 = mlog[(size_t)p * 2 + 1] + g1;
    midx[p] = (z1 > z0) ? 1 : 0;
}

// ---------------------------------------------------------------- per-batch cummax scan
__global__ void scan_kernel(const int* __restrict__ midx, int* __restrict__ rsel)
{
    __shared__ int sb[1024];
    int b = blockIdx.x, t = threadIdx.x;
    int flag = (t == 0) || (midx[b * 1024 + t] == 0);
    int v = flag ? t : -1;
    sb[t] = v;
    __syncthreads();
    for (int off = 1; off < 1024; off <<= 1) {
        int u = (t >= off) ? sb[t - off] : -1;
        __syncthreads();
        if (u > v) v = u;
        sb[t] = v;
        __syncthreads();
    }
    rsel[b * 1024 + t] = v;
}

// ---------------------------------------------------------------- output writer
__global__ __launch_bounds__(256) void writer_kernel(
    const float* __restrict__ klog, const float* __restrict__ mlog,
    const int* __restrict__ kidx, const int* __restrict__ midx,
    const int* __restrict__ rsel, float* __restrict__ out)
{
    int lane = threadIdx.x & 63;
    int p = blockIdx.x * 4 + (threadIdx.x >> 6);
    int b = p >> 10, t = p & 1023;

    float kl = (lane < NK) ? klog[(size_t)p * NK + lane] : -INFINITY;
    float mx = kl;
#pragma unroll
    for (int off = 1; off < 64; off <<= 1) mx = fmaxf(mx, __shfl_xor(mx, off));
    float e = (lane < NK) ? expf(kl - mx) : 0.f;
    float ssum = e;
#pragma unroll
    for (int off = 1; off < 64; off <<= 1) ssum += __shfl_xor(ssum, off);
    float soft = e / ssum;

    float z0 = mlog[(size_t)p * 2], z1 = mlog[(size_t)p * 2 + 1];
    float mmx = fmaxf(z0, z1);
    float e0 = expf(z0 - mmx), e1 = expf(z1 - mmx);
    float mp0 = e0 / (e0 + e1), mp1 = e1 / (e0 + e1);

    int r = rsel[p];
    int kc = kidx[b * 1024 + r];
    int hasprev = (t > 0);
    int kp = 0;
    if (hasprev) { int rp = rsel[p - 1]; kp = kidx[b * 1024 + rp]; }

    if (lane < NK) {
        out[OFF_SK + (size_t)p * NK + lane] = (lane == kc) ? 1.f : 0.f;
        float skl = (hasprev && lane == kp) ? 1.f : 0.f;
        out[OFF_KP + (size_t)p * NK + lane] = skl * mp1 + soft * mp0;
    }
    if (lane == 0) {
        int ms0 = (t == 0) ? 1 : ((midx[p] == 0) ? 1 : 0);
        out[OFF_MS + (size_t)p * 2]     = (float)ms0;
        out[OFF_MS + (size_t)p * 2 + 1] = (float)(1 - ms0);
        out[OFF_MP + (size_t)p * 2]     = mp0;
        out[OFF_MP + (size_t)p * 2 + 1] = mp1;
    }
}

// ---------------------------------------------------------------- host
extern "C" void kernel_launch(void* const* d_in, const int* in_sizes, int n_in,
                              void* d_out, int out_size, void* d_ws, size_t ws_size,
                              hipStream_t stream)
{
    (void)in_sizes; (void)n_in; (void)out_size; (void)ws_size;
    const float* state  = (const float*)d_in[0];
    const float* act    = (const float*)d_in[1];
    const float* goal   = (const float*)d_in[2];
    const float* u_m    = (const float*)d_in[4];
    const float* u_k    = (const float*)d_in[5];
    const float* W_in   = (const float*)d_in[6];
    const float* b_in   = (const float*)d_in[7];
    const float* Wqkv   = (const float*)d_in[8];
    const float* bqkv   = (const float*)d_in[9];
    const float* Wo     = (const float*)d_in[10];
    const float* bo     = (const float*)d_in[11];
    const float* ln1_g  = (const float*)d_in[12];
    const float* ln1_b  = (const float*)d_in[13];
    const float* W1     = (const float*)d_in[14];
    const float* b1     = (const float*)d_in[15];
    const float* W2     = (const float*)d_in[16];
    const float* b2     = (const float*)d_in[17];
    const float* ln2_g  = (const float*)d_in[18];
    const float* ln2_b  = (const float*)d_in[19];
    const float* W_out  = (const float*)d_in[20];
    const float* b_out  = (const float*)d_in[21];
    const float* W_k1   = (const float*)d_in[22];
    const float* b_k1   = (const float*)d_in[23];
    const float* W_sub  = (const float*)d_in[24];
    const float* b_sub  = (const float*)d_in[25];
    const float* W_term = (const float*)d_in[26];
    const float* b_term = (const float*)d_in[27];

    char* wsb = (char*)d_ws;
    float* x  = (float*)(wsb);                        // [0,32) MB residual
    char*  X2 = wsb + (size_t)32 * MB;                // [32,64): x-planes then ln1-out f32
    char*  BG = wsb + (size_t)64 * MB;                // [64,256) big arena

    float*    x2f    = (float*)X2;
    _Float16* xph    = (_Float16*)X2;                 // x planes (qkv-gemm A)
    _Float16* xpl    = xph + (size_t)T_TOT * DM;

    float*    qkvf   = (float*)BG;                    // [64,160) qkv f32 (ld 1536)
    _Float16* QHp    = (_Float16*)(wsb + (size_t)160 * MB);
    _Float16* QLp    = (_Float16*)(wsb + (size_t)176 * MB);
    _Float16* KHp    = (_Float16*)(wsb + (size_t)192 * MB);
    _Float16* KLp    = (_Float16*)(wsb + (size_t)208 * MB);
    _Float16* VHp    = (_Float16*)(wsb + (size_t)224 * MB);
    _Float16* VLp    = (_Float16*)(wsb + (size_t)240 * MB);
    _Float16* wqh    = (_Float16*)(wsb + (size_t)160 * MB);  // transient, pre-conv_qkv
    _Float16* wql    = wqh + (size_t)DM * 3 * DM;

    float*    attno  = (float*)BG;                    // [64,96) attn out f32 (ld 512)
    _Float16* aoh    = (_Float16*)(wsb + (size_t)96 * MB);
    _Float16* aol    = (_Float16*)(wsb + (size_t)112 * MB);
    _Float16* woh    = (_Float16*)(wsb + (size_t)128 * MB);
    _Float16* wol    = woh + (size_t)DM * DM;

    _Float16* ffah   = (_Float16*)BG;                 // [64,96) ln1-out planes
    _Float16* ffal   = ffah + (size_t)T_TOT * DM;
    _Float16* w1h    = (_Float16*)(wsb + (size_t)96 * MB);
    _Float16* w1l    = w1h + (size_t)DM * DFF;
    _Float16* w2h    = (_Float16*)(wsb + (size_t)100 * MB);
    _Float16* w2l    = w2h + (size_t)DFF * DM;
    float*    midf   = (float*)(wsb + (size_t)104 * MB);     // 8192x2048 f32
    _Float16* mph    = (_Float16*)(wsb + (size_t)168 * MB);
    _Float16* mpl    = (_Float16*)(wsb + (size_t)200 * MB);

    // embed-phase buffers
    float*    feats  = (float*)BG;                    // [64,~101) feats f32 (ld 576)
    _Float16* fph    = (_Float16*)(wsb + (size_t)104 * MB);
    _Float16* fpl    = (_Float16*)(wsb + (size_t)124 * MB);
    _Float16* winh   = (_Float16*)(wsb + (size_t)144 * MB);
    _Float16* winl   = winh + (size_t)DIN * DM;

    // head-phase buffers
    _Float16* hph    = (_Float16*)BG;                 // [64,96) x planes
    _Float16* hpl    = hph + (size_t)T_TOT * DM;
    _Float16* wouth  = (_Float16*)(wsb + (size_t)96 * MB);
    _Float16* woutl  = wouth + (size_t)DM * 128;
    float*    out128 = (float*)(wsb + (size_t)100 * MB);
    _Float16* o2h    = (_Float16*)(wsb + (size_t)108 * MB);
    _Float16* o2l    = (_Float16*)(wsb + (size_t)112 * MB);
    _Float16* wk1h   = (_Float16*)(wsb + (size_t)116 * MB);
    _Float16* wk1l   = wk1h + (size_t)128 * 128;
    float*    hid128 = (float*)(wsb + (size_t)120 * MB);
    float*    klog   = (float*)(wsb + (size_t)128 * MB);
    float*    mlog   = (float*)(wsb + (size_t)132 * MB);
    int*      kidx   = (int*)(wsb + (size_t)136 * MB);
    int*      midx   = kidx + 16384;
    int*      rsel   = midx + 16384;

    // ---- embed
    concat_kernel<<<9216, 256, 0, stream>>>(state, act, goal, feats);
    conv_act<<<dim3(DIN / 32, T_TOT / 256), 256, 0, stream>>>(feats, DIN, fph, fpl, T_TOT);
    conv_w<<<dim3(DM / 128, DIN / 32), 256, 0, stream>>>(W_in, DM, winh, winl);
    gemm_mfma<<<dim3(DM / 128, T_TOT / 128), 256, 0, stream>>>(
        fph, fpl, winh, winl, b_in, x, DM, T_TOT, DM, DIN, 0, 0, 0);

    for (int l = 0; l < 3; ++l) {
        // qkv
        conv_w<<<dim3(3 * DM / 128, DM / 32), 256, 0, stream>>>(
            Wqkv + (size_t)l * DM * 3 * DM, 3 * DM, wqh, wql);
        conv_act<<<dim3(DM / 32, T_TOT / 256), 256, 0, stream>>>(x, DM, xph, xpl, T_TOT);
        gemm_mfma<<<dim3(3 * DM / 128, T_TOT / 128), 256, 0, stream>>>(
            xph, xpl, wqh, wql, bqkv + (size_t)l * 3 * DM, qkvf, 1536, T_TOT, 3 * DM, DM, 0, 0, 0);
        // attention
        conv_qkv<<<dim3(16, NHEAD, B_SZ), 256, 0, stream>>>(qkvf, QHp, QLp, KHp, KLp, VHp, VLp);
        attn_mfma<<<dim3(16, NHEAD, B_SZ), 256, 0, stream>>>(QHp, QLp, KHp, KLp, VHp, VLp, attno);
        // Wo projection + ln1
        conv_act<<<dim3(DM / 32, T_TOT / 256), 256, 0, stream>>>(attno, DM, aoh, aol, T_TOT);
        conv_w<<<dim3(DM / 128, DM / 32), 256, 0, stream>>>(Wo + (size_t)l * DM * DM, DM, woh, wol);
        gemm_mfma<<<dim3(DM / 128, T_TOT / 128), 256, 0, stream>>>(
            aoh, aol, woh, wol, bo + (size_t)l * DM, x2f, DM, T_TOT, DM, DM, 0, 0, 0);
        add_ln<<<T_TOT, 256, 0, stream>>>(x, x2f, ln1_g + (size_t)l * DM, ln1_b + (size_t)l * DM, x2f);
        // FFN (2 row-chunks of 8192)
        conv_act<<<dim3(DM / 32, T_TOT / 256), 256, 0, stream>>>(x2f, DM, ffah, ffal, T_TOT);
        conv_w<<<dim3(DFF / 128, DM / 32), 256, 0, stream>>>(W1 + (size_t)l * DM * DFF, DFF, w1h, w1l);
        conv_w<<<dim3(DM / 128, DFF / 32), 256, 0, stream>>>(W2 + (size_t)l * DFF * DM, DM, w2h, w2l);
        for (int c = 0; c < 2; ++c) {
            gemm_mfma<<<dim3(DFF / 128, 64), 256, 0, stream>>>(
                ffah, ffal, w1h, w1l, b1 + (size_t)l * DFF, midf, DFF,
                T_TOT, DFF, DM, 1, c * 64, c * 8192);
            conv_act<<<dim3(DFF / 32, 8192 / 256), 256, 0, stream>>>(midf, DFF, mph, mpl, 8192);
            gemm_mfma<<<dim3(DM / 128, 64), 256, 0, stream>>>(
                mph, mpl, w2h, w2l, b2 + (size_t)l * DM, x + (size_t)c * 8192 * DM, DM,
                8192, DM, DFF, 0, 0, 0);
        }
        add_ln<<<T_TOT, 256, 0, stream>>>(x2f, x, ln2_g + (size_t)l * DM, ln2_b + (size_t)l * DM, x);
    }

    // ---- heads
    conv_act<<<dim3(DM / 32, T_TOT / 256), 256, 0, stream>>>(x, DM, hph, hpl, T_TOT);
    conv_w<<<dim3(1, DM / 32), 256, 0, stream>>>(W_out, 128, wouth, woutl);
    gemm_mfma<<<dim3(1, T_TOT / 128), 256, 0, stream>>>(
        hph, hpl, wouth, woutl, b_out, out128, 128, T_TOT, 128, DM, 0, 0, 0);
    conv_act<<<dim3(128 / 32, T_TOT / 256), 256, 0, stream>>>(out128, 128, o2h, o2l, T_TOT);
    conv_w<<<dim3(1, 128 / 32), 256, 0, stream>>>(W_k1, 128, wk1h, wk1l);
    gemm_mfma<<<dim3(1, T_TOT / 128), 256, 0, stream>>>(
        o2h, o2l, wk1h, wk1l, b_k1, hid128, 128, T_TOT, 128, 128, 1, 0, 0);
    gemm_f32<<<dim3(1, T_TOT / 128), 256, 0, stream>>>(hid128, 128, W_sub, b_sub, klog, NK, T_TOT, 128, NK, 0);
    gemm_f32<<<dim3(1, T_TOT / 128), 256, 0, stream>>>(out128, 128, W_term, b_term, mlog, 2, T_TOT, 128, 2, 0);

    gumbel_k_kernel<<<T_TOT / 4, 256, 0, stream>>>(klog, u_k, kidx);
    gumbel_m_kernel<<<T_TOT / 256, 256, 0, stream>>>(mlog, u_m, midx);
    scan_kernel<<<B_SZ, 1024, 0, stream>>>(midx, rsel);
    writer_kernel<<<T_TOT / 4, 256, 0, stream>>>(klog, mlog, kidx, midx, rsel, (float*)d_out);
}